// Round 6
// baseline (195.632 us; speedup 1.0000x reference)
//
#include <hip/hip_runtime.h>

// Problem constants (from reference)
#define KSIZE   32
#define KSTRIDE 16
#define HK      4
#define HD      128
#define ROW     (HK * HD)                       // 512 floats per token
#define ROW4    (ROW / 4)                       // 128 float4 per token
#define BATCH   4
#define SEQLEN  16384
#define CHUNKS_PER_BATCH ((SEQLEN - KSIZE) / KSTRIDE + 1)   // 1023
#define TOTAL_CHUNKS     (BATCH * CHUNKS_PER_BATCH)         // 4092
#define HW_PER_BATCH     (SEQLEN / KSTRIDE)                 // 1024 half-windows
#define TOTAL_HW         (BATCH * HW_PER_BATCH)             // 4096
#define WS_FLOATS        ((size_t)TOTAL_HW * ROW)           // 2M floats, 8.39MB

// Two-phase decomposition. Evidence from R0-R4: effective BW tracks waves/CU
// (5.9 TB/s at 32 w/CU in R2, 4.0 at 4 w/CU in R3) because per-wave in-flight
// loads are bounded; the serial-carry structure tied byte-minimality to low
// occupancy. Half-window sums H[j] are independent -> phase 1 is a pure
// full-width stream reading every input byte exactly once (R2's proven-BW
// shape, zero duplication); phase 2 combines adjacent H into chunk means.

// Phase 1: one 16-row half-window per 128-thread block. Contiguous 32KB read,
// 2KB write. 4096 blocks = 32 waves/CU.
__global__ __launch_bounds__(128)
void hw_sums(const float* __restrict__ k,
             const int* __restrict__ cu_seqlens,
             float* __restrict__ H) {
    const int j  = blockIdx.x;                  // half-window id 0..4095
    const int b  = j >> 10;                     // batch
    const int hw = j & (HW_PER_BATCH - 1);      // half-window within batch
    const float4* __restrict__ src = (const float4*)
        (k + ((long)cu_seqlens[b] + (long)hw * KSTRIDE) * ROW);
    const int t = threadIdx.x;                  // float4 column 0..127

    float4 a0 = make_float4(0.f, 0.f, 0.f, 0.f);
    float4 a1 = make_float4(0.f, 0.f, 0.f, 0.f);
    #pragma unroll
    for (int r = 0; r < KSTRIDE; r += 2) {
        float4 u = src[(long)r * ROW4 + t];
        float4 v = src[(long)(r + 1) * ROW4 + t];
        a0.x += u.x; a0.y += u.y; a0.z += u.z; a0.w += u.w;
        a1.x += v.x; a1.y += v.y; a1.z += v.z; a1.w += v.w;
    }
    float4 s = make_float4(a0.x + a1.x, a0.y + a1.y, a0.z + a1.z, a0.w + a1.w);
    ((float4*)(H + (long)j * ROW))[t] = s;
}

// Phase 2: out[chunk] = (H[c] + H[c+1]) / 32. 523776 float4 elements total;
// 256 threads/block, one float4 each. H reads are L2-warm.
__global__ __launch_bounds__(256)
void hw_combine(const float* __restrict__ H,
                const int* __restrict__ cu_seqlens,
                float* __restrict__ out,
                float* __restrict__ tail) {
    const int idx = blockIdx.x * 256 + threadIdx.x;      // 0..524287
    if (idx < TOTAL_CHUNKS * ROW4) {
        const int chunk = idx >> 7;                      // 0..4091
        const int col   = idx & (ROW4 - 1);
        const int b     = chunk / CHUNKS_PER_BATCH;
        const int c     = chunk - b * CHUNKS_PER_BATCH;

        const long h = ((long)(b * HW_PER_BATCH + c)) * ROW4 + col;
        float4 u = ((const float4*)H)[h];
        float4 v = ((const float4*)H)[h + ROW4];
        const float s = 1.0f / (float)KSIZE;
        float4 r = make_float4((u.x + v.x) * s, (u.y + v.y) * s,
                               (u.z + v.z) * s, (u.w + v.w) * s);
        ((float4*)out)[(long)chunk * ROW4 + col] = r;
    }

    // Fused cu_comp tail write (fp32 representation in the flat out buffer).
    if (idx == 0) {
        int run = 0;
        tail[0] = 0.0f;
        #pragma unroll
        for (int i = 0; i < BATCH; ++i) {
            const int len = cu_seqlens[i + 1] - cu_seqlens[i];
            const int n = (len >= KSIZE) ? (len - KSIZE) / KSTRIDE + 1 : 0;
            run += n;
            tail[i + 1] = (float)run;
        }
    }
}

// Fallback (R3 structure) if workspace is too small: SPAN=8 sequential carry.
#define SPAN 8
#define FB_BLOCKS_PER_BATCH ((CHUNKS_PER_BATCH + SPAN - 1) / SPAN)  // 128
#define FB_TOTAL_BLOCKS     (BATCH * FB_BLOCKS_PER_BATCH)          // 512

__device__ __forceinline__ float4 sum16(const float4* __restrict__ src,
                                        int row0, int t) {
    float4 a0 = make_float4(0.f, 0.f, 0.f, 0.f);
    float4 a1 = make_float4(0.f, 0.f, 0.f, 0.f);
    #pragma unroll
    for (int i = 0; i < 8; ++i) {
        float4 u = src[(long)(row0 + 2 * i)     * ROW4 + t];
        float4 v = src[(long)(row0 + 2 * i + 1) * ROW4 + t];
        a0.x += u.x; a0.y += u.y; a0.z += u.z; a0.w += u.w;
        a1.x += v.x; a1.y += v.y; a1.z += v.z; a1.w += v.w;
    }
    a0.x += a1.x; a0.y += a1.y; a0.z += a1.z; a0.w += a1.w;
    return a0;
}

__global__ __launch_bounds__(128)
void compress_k_fallback(const float* __restrict__ k,
                         const int* __restrict__ cu_seqlens,
                         float* __restrict__ out,
                         float* __restrict__ tail) {
    const int blk = blockIdx.x;
    const int b   = blk / FB_BLOCKS_PER_BATCH;
    const int cb  = blk - b * FB_BLOCKS_PER_BATCH;
    const int c0  = cb * SPAN;
    const int gc  = (CHUNKS_PER_BATCH - c0 < SPAN) ? (CHUNKS_PER_BATCH - c0)
                                                   : SPAN;
    const float4* __restrict__ src = (const float4*)
        (k + ((long)cu_seqlens[b] + (long)c0 * KSTRIDE) * ROW);
    const int t = threadIdx.x;
    const float s = 1.0f / (float)KSIZE;
    float* outp = out + (long)(b * CHUNKS_PER_BATCH + c0) * ROW;

    float4 prev = sum16(src, 0, t);
    for (int g = 0; g < gc; ++g) {
        float4 cur = sum16(src, (g + 1) * KSTRIDE, t);
        float4 r = make_float4((prev.x + cur.x) * s, (prev.y + cur.y) * s,
                               (prev.z + cur.z) * s, (prev.w + cur.w) * s);
        ((float4*)(outp + (long)g * ROW))[t] = r;
        prev = cur;
    }
    if (blk == 0 && t == 0) {
        int run = 0;
        tail[0] = 0.0f;
        #pragma unroll
        for (int i = 0; i < BATCH; ++i) {
            const int len = cu_seqlens[i + 1] - cu_seqlens[i];
            const int n = (len >= KSIZE) ? (len - KSIZE) / KSTRIDE + 1 : 0;
            run += n;
            tail[i + 1] = (float)run;
        }
    }
}

extern "C" void kernel_launch(void* const* d_in, const int* in_sizes, int n_in,
                              void* d_out, int out_size, void* d_ws, size_t ws_size,
                              hipStream_t stream) {
    const float* k          = (const float*)d_in[0];
    const int*   cu_seqlens = (const int*)d_in[1];
    float*       out        = (float*)d_out;
    float*       tail       = out + (long)TOTAL_CHUNKS * ROW;

    if (ws_size >= WS_FLOATS * sizeof(float) && d_ws != nullptr) {
        float* H = (float*)d_ws;
        hw_sums<<<TOTAL_HW, 128, 0, stream>>>(k, cu_seqlens, H);
        const int p2_threads = TOTAL_CHUNKS * ROW4;          // 523776
        const int p2_blocks  = (p2_threads + 255) / 256;     // 2046
        hw_combine<<<p2_blocks, 256, 0, stream>>>(H, cu_seqlens, out, tail);
    } else {
        compress_k_fallback<<<FB_TOTAL_BLOCKS, 128, 0, stream>>>(
            k, cu_seqlens, out, tail);
    }
}